// Round 8
// baseline (297.854 us; speedup 1.0000x reference)
//
#include <hip/hip_runtime.h>
#include <hip/hip_bf16.h>

#define AS1 __attribute__((address_space(1)))
#define AS3 __attribute__((address_space(3)))

typedef __bf16 bf16x8 __attribute__((ext_vector_type(8)));
typedef float f32x4 __attribute__((ext_vector_type(4)));

#define GLOAD_LDS16(gptr, lptr) \
  __builtin_amdgcn_global_load_lds((AS1 void*)(gptr), (AS3 void*)(lptr), 16, 0, 0)

#define M_W   4096
#define K_DIM 4096
#define M_X   8192
#define NT_T  65536
#define NKT   (K_DIM/64)

#define BAR()    __builtin_amdgcn_s_barrier()
#define SCHED0() __builtin_amdgcn_sched_barrier(0)
#define VMW6()   asm volatile("s_waitcnt vmcnt(6)" ::: "memory")
#define VMW0()   asm volatile("s_waitcnt vmcnt(0)" ::: "memory")

template<int N> __device__ __forceinline__ void lgkmw() {
  if constexpr (N == 0)       asm volatile("s_waitcnt lgkmcnt(0)" ::: "memory");
  else if constexpr (N == 4)  asm volatile("s_waitcnt lgkmcnt(4)" ::: "memory");
  else if constexpr (N == 8)  asm volatile("s_waitcnt lgkmcnt(8)" ::: "memory");
  else                        asm volatile("s_waitcnt lgkmcnt(12)" ::: "memory");
}

__device__ __forceinline__ unsigned short f2bf(float f) {
  unsigned int u = __float_as_uint(f);
  unsigned int r = (u + 0x7FFFu + ((u >> 16) & 1u)) >> 16;
  return (unsigned short)r;
}

// ---------------- fused prep: x fp32->bf16 (1/3 of blocks) + trellis decode (2/3) ----------------
__global__ void prep_kernel(const float* __restrict__ x,
                            const int* __restrict__ trellis,
                            const float* __restrict__ tlut,
                            unsigned short* __restrict__ xb,
                            unsigned short* __restrict__ W) {
  int b = blockIdx.x;
  int tid = threadIdx.x;
  if (b % 3 == 0) {
    int idx = (b / 3) * 256 + tid;
    const float4* p = reinterpret_cast<const float4*>(x) + (size_t)idx * 2;
    float4 u = p[0];
    float4 v = p[1];
    uint4 o;
    o.x = (unsigned)f2bf(u.x) | ((unsigned)f2bf(u.y) << 16);
    o.y = (unsigned)f2bf(u.z) | ((unsigned)f2bf(u.w) << 16);
    o.z = (unsigned)f2bf(v.x) | ((unsigned)f2bf(v.y) << 16);
    o.w = (unsigned)f2bf(v.z) | ((unsigned)f2bf(v.w) << 16);
    reinterpret_cast<uint4*>(xb)[idx] = o;
  } else {
    int db = b - b / 3 - 1;
    int idx = db * 256 + tid;
    int t = idx >> 7;
    int s = idx & 127;
    const unsigned int* tr = reinterpret_cast<const unsigned int*>(trellis) + t * 32;
    int w0  = s >> 2;
    int off = (s & 3) * 4;
    unsigned int a = tr[w0] & 0xFFFFu;
    unsigned int state;
    if (off == 0) {
      state = a;
    } else {
      unsigned int bb = tr[(w0 + 1) & 31] & 0xFFFFu;
      state = ((a << off) | (bb >> (16 - off))) & 0xFFFFu;
    }
    unsigned int code = state & 0x1FFu;
    float2 v = reinterpret_cast<const float2*>(tlut)[code];
    int i = t >> 8;
    int j = t & 255;
    int flat = s * 2;
    int r = flat >> 4;
    int c = flat & 15;
    unsigned int packed = (unsigned)f2bf(v.x) | ((unsigned)f2bf(v.y) << 16);
    size_t o = (size_t)(i * 16 + r) * K_DIM + (j * 16 + c);
    *reinterpret_cast<unsigned int*>(W + o) = packed;
  }
}

// ---------------- 256x256 8-phase GEMM, parity-staggered read-ahead ----------------
// LDS slots: A(buf,half) = (buf*2+half)*16384 ; B(buf,half) = 65536 + (buf*2+half)*16384
// Half-tile: 128 rows x 64 cols bf16, 16B chunks XOR-swizzled (chunk ^= row&7).
// Reads of phase p feed MFMA of phase p+1. Parity-A waves: reads;stage;lgkm(R);MFMA.
// Parity-B waves: lgkm(0);MFMA;reads;stage. One barrier + VMW(6) per phase.
// Stage calendar (per iter): ph1 b1A1<-t1 | ph2 b0A0<-t2 | ph3 b0B0<-t2 | ph4 b0B1<-t2
//                            ph5 b0A1<-t2 | ph6 b1A0<-t3 | ph7 b1B0<-t3 | ph8 b1B1<-t3
// min stage->ds_read margin = 4 phases; gate VMW(6) (2 gloads/phase) forces >=4-back complete.

template<int BUF, int MH>
__device__ __forceinline__ void lda(const char* ldsc, const int* aRow, const int* kOff,
                                    bf16x8 (&af)[4][2]) {
  const char* base = ldsc + (BUF * 2 + MH) * 16384;
  #pragma unroll
  for (int fm = 0; fm < 4; ++fm)
    #pragma unroll
    for (int kh = 0; kh < 2; ++kh)
      af[fm][kh] = *(const bf16x8*)(base + aRow[fm] + kOff[kh]);
}

template<int BUF, int NH>
__device__ __forceinline__ void ldb(const char* ldsc, const int* bRow, const int* kOff,
                                    bf16x8 (&bq)[2][2]) {
  const char* base = ldsc + 65536 + (BUF * 2 + NH) * 16384;
  #pragma unroll
  for (int fn = 0; fn < 2; ++fn)
    #pragma unroll
    for (int kh = 0; kh < 2; ++kh)
      bq[fn][kh] = *(const bf16x8*)(base + bRow[fn] + kOff[kh]);
}

template<int MH, int NH>
__device__ __forceinline__ void mm(const bf16x8 (&af)[4][2], const bf16x8 (&bq)[2][2],
                                   f32x4 (&acc)[8][4]) {
  __builtin_amdgcn_s_setprio(1);
  #pragma unroll
  for (int fm = 0; fm < 4; ++fm)
    #pragma unroll
    for (int fn = 0; fn < 2; ++fn)
      #pragma unroll
      for (int kh = 0; kh < 2; ++kh)
        acc[MH * 4 + fm][NH * 2 + fn] =
            __builtin_amdgcn_mfma_f32_16x16x32_bf16(af[fm][kh], bq[fn][kh],
                                                    acc[MH * 4 + fm][NH * 2 + fn], 0, 0, 0);
  __builtin_amdgcn_s_setprio(0);
}

template<int BUF, int HALF>
__device__ __forceinline__ void stA(const unsigned short* xb, char* ldsc, int kt,
                                    int gArow0, int gArow1, int gcol, int lo0) {
  const unsigned short* s0 = xb + (size_t)(gArow0 + HALF * 64) * K_DIM + kt * 64 + gcol;
  const unsigned short* s1 = xb + (size_t)(gArow1 + HALF * 64) * K_DIM + kt * 64 + gcol;
  GLOAD_LDS16(s0, ldsc + (BUF * 2 + HALF) * 16384 + lo0);
  GLOAD_LDS16(s1, ldsc + (BUF * 2 + HALF) * 16384 + lo0 + 1024);
}

template<int BUF, int HALF>
__device__ __forceinline__ void stB(const unsigned short* W, char* ldsc, int kt,
                                    int gBrow0, int gBrow1, int gcol, int lo0) {
  const unsigned short* s0 = W + (size_t)(gBrow0 + HALF * 32) * K_DIM + kt * 64 + gcol;
  const unsigned short* s1 = W + (size_t)(gBrow1 + HALF * 32) * K_DIM + kt * 64 + gcol;
  GLOAD_LDS16(s0, ldsc + 65536 + (BUF * 2 + HALF) * 16384 + lo0);
  GLOAD_LDS16(s1, ldsc + 65536 + (BUF * 2 + HALF) * 16384 + lo0 + 1024);
}

// Phase body helper macro: RD = reads for next phase, ST = stage, LG = lgkm count, MMCALL
#define PHASE(RD, ST, LG, MMCALL)                         \
  if (PA) {                                               \
    RD; ST; SCHED0(); lgkmw<LG>(); SCHED0();              \
    MMCALL;                                               \
  } else {                                                \
    lgkmw<0>(); SCHED0();                                 \
    MMCALL;                                               \
    SCHED0(); RD; ST;                                     \
  }                                                       \
  VMW6(); BAR();

template<bool PA>
__device__ __forceinline__ void kloop(const unsigned short* __restrict__ xb,
                                      const unsigned short* __restrict__ W,
                                      char* ldsc, const int* aRow, const int* bRow,
                                      const int* kOff, int gArow0, int gArow1,
                                      int gBrow0, int gBrow1, int gcol, int lo0,
                                      bf16x8 (&afA)[4][2], bf16x8 (&afB)[4][2],
                                      bf16x8 (&bqX)[2][2], bf16x8 (&bqY)[2][2],
                                      f32x4 (&acc)[8][4]) {
  #pragma unroll 1
  for (int i = 0; i < NKT / 2; ++i) {
    int t1 = 2 * i + 1;
    int t2 = 2 * i + 2; if (t2 > NKT - 1) t2 = NKT - 1;
    int t3 = 2 * i + 3; if (t3 > NKT - 1) t3 = NKT - 1;

    // ph1: MFMA e(0,0)[afA,bqX]; rd A1e->afB
    PHASE((lda<0,1>(ldsc, aRow, kOff, afB)),
          (stA<1,1>(xb, ldsc, t1, gArow0, gArow1, gcol, lo0)), 8,
          (mm<0,0>(afA, bqX, acc)));
    // ph2: MFMA e(1,0)[afB,bqX]; rd B1e->bqY
    PHASE((ldb<0,1>(ldsc, bRow, kOff, bqY)),
          (stA<0,0>(xb, ldsc, t2, gArow0, gArow1, gcol, lo0)), 4,
          (mm<1,0>(afB, bqX, acc)));
    // ph3: MFMA e(1,1)[afB,bqY]; no reads
    PHASE(, (stB<0,0>(W, ldsc, t2, gBrow0, gBrow1, gcol, lo0)), 0,
          (mm<1,1>(afB, bqY, acc)));
    // ph4: MFMA e(0,1)[afA,bqY]; rd A0o->afB, B0o->bqX
    PHASE((lda<1,0>(ldsc, aRow, kOff, afB), ldb<1,0>(ldsc, bRow, kOff, bqX)),
          (stB<0,1>(W, ldsc, t2, gBrow0, gBrow1, gcol, lo0)), 12,
          (mm<0,1>(afA, bqY, acc)));
    // ph5: MFMA o(0,0)[afB,bqX]; rd A1o->afA
    PHASE((lda<1,1>(ldsc, aRow, kOff, afA)),
          (stA<0,1>(xb, ldsc, t2, gArow0, gArow1, gcol, lo0)), 8,
          (mm<0,0>(afB, bqX, acc)));
    // ph6: MFMA o(1,0)[afA,bqX]; rd B1o->bqY
    PHASE((ldb<1,1>(ldsc, bRow, kOff, bqY)),
          (stA<1,0>(xb, ldsc, t3, gArow0, gArow1, gcol, lo0)), 4,
          (mm<1,0>(afA, bqX, acc)));
    // ph7: MFMA o(1,1)[afA,bqY]; no reads
    PHASE(, (stB<1,0>(W, ldsc, t3, gBrow0, gBrow1, gcol, lo0)), 0,
          (mm<1,1>(afA, bqY, acc)));
    // ph8: MFMA o(0,1)[afB,bqY]; rd A0e''->afA, B0e''->bqX
    PHASE((lda<0,0>(ldsc, aRow, kOff, afA), ldb<0,0>(ldsc, bRow, kOff, bqX)),
          (stB<1,1>(W, ldsc, t3, gBrow0, gBrow1, gcol, lo0)), 12,
          (mm<0,1>(afB, bqY, acc)));
  }
}

__global__ __launch_bounds__(512) void gemm8_kernel(const unsigned short* __restrict__ xb,
                                                    const unsigned short* __restrict__ W,
                                                    float* __restrict__ y) {
  extern __shared__ __align__(16) char ldsc[];   // 131072 bytes

  int bid = blockIdx.x;
  int swz = (bid & 7) * 64 + (bid >> 3);
  int brow = (swz >> 4) * 256;
  int bcol = (swz & 15) * 256;

  int tid  = threadIdx.x;
  int lane = tid & 63;
  int wid  = tid >> 6;
  int wr = wid >> 2;
  int wc = wid & 3;
  bool parA = ((wid ^ (wid >> 2)) & 1) == 0;   // splits SIMD-mates under either mapping

  int kOff[2], aRow[4], bRow[2];
  #pragma unroll
  for (int kh = 0; kh < 2; ++kh) kOff[kh] = ((kh * 4 + (lane >> 4)) ^ (lane & 7)) << 4;
  #pragma unroll
  for (int fm = 0; fm < 4; ++fm) aRow[fm] = (wr * 64 + fm * 16 + (lane & 15)) << 7;
  #pragma unroll
  for (int fn = 0; fn < 2; ++fn) bRow[fn] = (wc * 32 + fn * 16 + (lane & 15)) << 7;

  int q0 = wid * 16 + (lane >> 3);
  int q1 = q0 + 8;
  int lo0 = wid * 2048 + lane * 16;
  int gcol = ((lane & 7) ^ (lane >> 3)) << 3;
  int gArow0 = brow + (q0 >> 6) * 128 + (q0 & 63);
  int gArow1 = brow + (q1 >> 6) * 128 + (q1 & 63);
  int gBrow0 = bcol + (q0 >> 5) * 64 + (q0 & 31);
  int gBrow1 = bcol + (q1 >> 5) * 64 + (q1 & 31);

  f32x4 acc[8][4];
  #pragma unroll
  for (int m = 0; m < 8; ++m)
    #pragma unroll
    for (int n = 0; n < 4; ++n)
      acc[m][n] = (f32x4){0.f, 0.f, 0.f, 0.f};

  bf16x8 afA[4][2], afB[4][2];
  bf16x8 bqX[2][2], bqY[2][2];

  // prologue: buf0 <- t0 (all four), buf1 <- t1 (A0,B0,B1); buf1-A1 staged in ph1
  stA<0,0>(xb, ldsc, 0, gArow0, gArow1, gcol, lo0);
  stB<0,0>(W,  ldsc, 0, gBrow0, gBrow1, gcol, lo0);
  stB<0,1>(W,  ldsc, 0, gBrow0, gBrow1, gcol, lo0);
  stA<0,1>(xb, ldsc, 0, gArow0, gArow1, gcol, lo0);
  stA<1,0>(xb, ldsc, 1, gArow0, gArow1, gcol, lo0);
  stB<1,0>(W,  ldsc, 1, gBrow0, gBrow1, gcol, lo0);
  stB<1,1>(W,  ldsc, 1, gBrow0, gBrow1, gcol, lo0);
  VMW0(); BAR();

  // preloop reads for ph1: afA <- A0(t0), bqX <- B0(t0)
  lda<0,0>(ldsc, aRow, kOff, afA);
  ldb<0,0>(ldsc, bRow, kOff, bqX);

  if (parA)
    kloop<true>(xb, W, ldsc, aRow, bRow, kOff, gArow0, gArow1, gBrow0, gBrow1,
                gcol, lo0, afA, afB, bqX, bqY, acc);
  else
    kloop<false>(xb, W, ldsc, aRow, bRow, kOff, gArow0, gArow1, gBrow0, gBrow1,
                 gcol, lo0, afA, afB, bqX, bqY, acc);

  VMW0();

  // epilogue: C/D layout col=lane&15, row=(lane>>4)*4+j
  #pragma unroll
  for (int am = 0; am < 8; ++am) {
    #pragma unroll
    for (int an = 0; an < 4; ++an) {
      int row0 = brow + wr * 128 + am * 16 + (lane >> 4) * 4;
      int col  = bcol + wc * 64 + an * 16 + (lane & 15);
      #pragma unroll
      for (int j = 0; j < 4; ++j)
        y[(size_t)(row0 + j) * M_W + col] = acc[am][an][j];
    }
  }
}

extern "C" void kernel_launch(void* const* d_in, const int* in_sizes, int n_in,
                              void* d_out, int out_size, void* d_ws, size_t ws_size,
                              hipStream_t stream) {
  const float* inp     = (const float*)d_in[0];
  const int*   trellis = (const int*)d_in[1];
  const float* tlut    = (const float*)d_in[2];
  float* y = (float*)d_out;

  unsigned short* xb = (unsigned short*)d_ws;
  unsigned short* Wd = (unsigned short*)((char*)d_ws + (size_t)M_X * K_DIM * 2);

  (void)hipFuncSetAttribute((const void*)gemm8_kernel,
                            hipFuncAttributeMaxDynamicSharedMemorySize, 131072);

  prep_kernel<<<49152, 256, 0, stream>>>(inp, trellis, tlut, xb, Wd);
  gemm8_kernel<<<dim3(512), dim3(512), 131072, stream>>>(xb, Wd, y);
}

// Round 9
// 269.750 us; speedup vs baseline: 1.1042x; 1.1042x over previous
//
#include <hip/hip_runtime.h>
#include <hip/hip_bf16.h>

#define AS1 __attribute__((address_space(1)))
#define AS3 __attribute__((address_space(3)))

typedef __bf16 bf16x8 __attribute__((ext_vector_type(8)));
typedef float f32x4 __attribute__((ext_vector_type(4)));

#define GLOAD_LDS16(gptr, lptr) \
  __builtin_amdgcn_global_load_lds((AS1 void*)(gptr), (AS3 void*)(lptr), 16, 0, 0)

#define M_W   4096
#define K_DIM 4096
#define M_X   8192
#define NT_T  65536
#define NKT   (K_DIM/64)

#define BAR()        __builtin_amdgcn_s_barrier()
#define WAIT_LGKM0() asm volatile("s_waitcnt lgkmcnt(0)" ::: "memory")
#define WAIT_LGKM8() asm volatile("s_waitcnt lgkmcnt(8)" ::: "memory")
#define WAIT_VM4()   asm volatile("s_waitcnt vmcnt(4)" ::: "memory")
#define WAIT_VM0()   asm volatile("s_waitcnt vmcnt(0)" ::: "memory")

__device__ __forceinline__ unsigned short f2bf(float f) {
  unsigned int u = __float_as_uint(f);
  unsigned int r = (u + 0x7FFFu + ((u >> 16) & 1u)) >> 16;
  return (unsigned short)r;
}

// ---------------- fused prep: x fp32->bf16 (1/3 of blocks) + trellis decode (2/3) ----------------
__global__ void prep_kernel(const float* __restrict__ x,
                            const int* __restrict__ trellis,
                            const float* __restrict__ tlut,
                            unsigned short* __restrict__ xb,
                            unsigned short* __restrict__ W) {
  int b = blockIdx.x;
  int tid = threadIdx.x;
  if (b % 3 == 0) {
    int idx = (b / 3) * 256 + tid;
    const float4* p = reinterpret_cast<const float4*>(x) + (size_t)idx * 2;
    float4 u = p[0];
    float4 v = p[1];
    uint4 o;
    o.x = (unsigned)f2bf(u.x) | ((unsigned)f2bf(u.y) << 16);
    o.y = (unsigned)f2bf(u.z) | ((unsigned)f2bf(u.w) << 16);
    o.z = (unsigned)f2bf(v.x) | ((unsigned)f2bf(v.y) << 16);
    o.w = (unsigned)f2bf(v.z) | ((unsigned)f2bf(v.w) << 16);
    reinterpret_cast<uint4*>(xb)[idx] = o;
  } else {
    int db = b - b / 3 - 1;
    int idx = db * 256 + tid;
    int t = idx >> 7;
    int s = idx & 127;
    const unsigned int* tr = reinterpret_cast<const unsigned int*>(trellis) + t * 32;
    int w0  = s >> 2;
    int off = (s & 3) * 4;
    unsigned int a = tr[w0] & 0xFFFFu;
    unsigned int state;
    if (off == 0) {
      state = a;
    } else {
      unsigned int bb = tr[(w0 + 1) & 31] & 0xFFFFu;
      state = ((a << off) | (bb >> (16 - off))) & 0xFFFFu;
    }
    unsigned int code = state & 0x1FFu;
    float2 v = reinterpret_cast<const float2*>(tlut)[code];
    int i = t >> 8;
    int j = t & 255;
    int flat = s * 2;
    int r = flat >> 4;
    int c = flat & 15;
    unsigned int packed = (unsigned)f2bf(v.x) | ((unsigned)f2bf(v.y) << 16);
    size_t o = (size_t)(i * 16 + r) * K_DIM + (j * 16 + c);
    *reinterpret_cast<unsigned int*>(W + o) = packed;
  }
}

// ---------------- 256x256 4-phase bf16 GEMM (merged quadrant pairs) ----------------
// y[8192,4096] = xb[8192,4096] * W[4096,4096]^T
// LDS slots: A(buf,half) = (buf*2+half)*16384 ; B(buf,half) = 65536 + (buf*2+half)*16384
// Half-tile: 128 rows x 64 cols bf16, 16B chunks XOR-swizzled (chunk ^= row&7).
// Per iter (2 K-tiles e=2i buf0, o=2i+1 buf1), 4 phases of 32 MFMA:
//  ph1: buf0 M-half0 x {N0,N1}; reads A0(8)+B0(4)+B1(4); stage buf1.B1,A1 <- 2i+1
//  ph2: buf0 M-half1 x {N0,N1}; reads A1(8);              stage buf0.A0,B0 <- 2i+2
//  ph3: buf1 M-half0 x {N0,N1}; reads A0(8)+B0(4)+B1(4);  stage buf0.B1,A1 <- 2i+2
//  ph4: buf1 M-half1 x {N0,N1}; reads A1(8);              stage buf1.A0,B0 <- 2i+3
// vm(4) each phase end (4 gloads/phase) => prior-phase stages complete; min RAW margin 2 ph.

template<int BUF, int MH>
__device__ __forceinline__ void lda(const char* ldsc, const int* aRow, const int* kOff,
                                    bf16x8 (&af)[4][2]) {
  const char* base = ldsc + (BUF * 2 + MH) * 16384;
  #pragma unroll
  for (int fm = 0; fm < 4; ++fm)
    #pragma unroll
    for (int kh = 0; kh < 2; ++kh)
      af[fm][kh] = *(const bf16x8*)(base + aRow[fm] + kOff[kh]);
}

template<int BUF, int NH>
__device__ __forceinline__ void ldb(const char* ldsc, const int* bRow, const int* kOff,
                                    bf16x8 (&bq)[2][2]) {
  const char* base = ldsc + 65536 + (BUF * 2 + NH) * 16384;
  #pragma unroll
  for (int fn = 0; fn < 2; ++fn)
    #pragma unroll
    for (int kh = 0; kh < 2; ++kh)
      bq[fn][kh] = *(const bf16x8*)(base + bRow[fn] + kOff[kh]);
}

template<int MH, int NH>
__device__ __forceinline__ void mm(const bf16x8 (&af)[4][2], const bf16x8 (&bq)[2][2],
                                   f32x4 (&acc)[8][4]) {
  #pragma unroll
  for (int fm = 0; fm < 4; ++fm)
    #pragma unroll
    for (int fn = 0; fn < 2; ++fn)
      #pragma unroll
      for (int kh = 0; kh < 2; ++kh)
        acc[MH * 4 + fm][NH * 2 + fn] =
            __builtin_amdgcn_mfma_f32_16x16x32_bf16(af[fm][kh], bq[fn][kh],
                                                    acc[MH * 4 + fm][NH * 2 + fn], 0, 0, 0);
}

template<int BUF, int HALF>
__device__ __forceinline__ void stA(const unsigned short* xb, char* ldsc, int kt,
                                    int gArow0, int gArow1, int gcol, int lo0) {
  const unsigned short* s0 = xb + (size_t)(gArow0 + HALF * 64) * K_DIM + kt * 64 + gcol;
  const unsigned short* s1 = xb + (size_t)(gArow1 + HALF * 64) * K_DIM + kt * 64 + gcol;
  GLOAD_LDS16(s0, ldsc + (BUF * 2 + HALF) * 16384 + lo0);
  GLOAD_LDS16(s1, ldsc + (BUF * 2 + HALF) * 16384 + lo0 + 1024);
}

template<int BUF, int HALF>
__device__ __forceinline__ void stB(const unsigned short* W, char* ldsc, int kt,
                                    int gBrow0, int gBrow1, int gcol, int lo0) {
  const unsigned short* s0 = W + (size_t)(gBrow0 + HALF * 32) * K_DIM + kt * 64 + gcol;
  const unsigned short* s1 = W + (size_t)(gBrow1 + HALF * 32) * K_DIM + kt * 64 + gcol;
  GLOAD_LDS16(s0, ldsc + 65536 + (BUF * 2 + HALF) * 16384 + lo0);
  GLOAD_LDS16(s1, ldsc + 65536 + (BUF * 2 + HALF) * 16384 + lo0 + 1024);
}

__global__ __launch_bounds__(512) void gemm8_kernel(const unsigned short* __restrict__ xb,
                                                    const unsigned short* __restrict__ W,
                                                    float* __restrict__ y) {
  extern __shared__ __align__(16) char ldsc[];   // 131072 bytes

  int bid = blockIdx.x;
  int swz = (bid & 7) * 64 + (bid >> 3);
  int brow = (swz >> 4) * 256;
  int bcol = (swz & 15) * 256;

  int tid  = threadIdx.x;
  int lane = tid & 63;
  int wid  = tid >> 6;
  int wr = wid >> 2;
  int wc = wid & 3;

  int kOff[2], aRow[4], bRow[2];
  #pragma unroll
  for (int kh = 0; kh < 2; ++kh) kOff[kh] = ((kh * 4 + (lane >> 4)) ^ (lane & 7)) << 4;
  #pragma unroll
  for (int fm = 0; fm < 4; ++fm) aRow[fm] = (wr * 64 + fm * 16 + (lane & 15)) << 7;
  #pragma unroll
  for (int fn = 0; fn < 2; ++fn) bRow[fn] = (wc * 32 + fn * 16 + (lane & 15)) << 7;

  int q0 = wid * 16 + (lane >> 3);
  int q1 = q0 + 8;
  int lo0 = wid * 2048 + lane * 16;
  int gcol = ((lane & 7) ^ (lane >> 3)) << 3;
  int gArow0 = brow + (q0 >> 6) * 128 + (q0 & 63);
  int gArow1 = brow + (q1 >> 6) * 128 + (q1 & 63);
  int gBrow0 = bcol + (q0 >> 5) * 64 + (q0 & 31);
  int gBrow1 = bcol + (q1 >> 5) * 64 + (q1 & 31);

  f32x4 acc[8][4];
  #pragma unroll
  for (int m = 0; m < 8; ++m)
    #pragma unroll
    for (int n = 0; n < 4; ++n)
      acc[m][n] = (f32x4){0.f, 0.f, 0.f, 0.f};

  bf16x8 af[4][2];
  bf16x8 bq0[2][2], bq1[2][2];

  // prologue: buf0 <- t0 (A0,B0,B1,A1); buf1 <- t1 (A0,B0). buf1.B1/A1 staged at ph1.
  stA<0,0>(xb, ldsc, 0, gArow0, gArow1, gcol, lo0);
  stB<0,0>(W,  ldsc, 0, gBrow0, gBrow1, gcol, lo0);
  stB<0,1>(W,  ldsc, 0, gBrow0, gBrow1, gcol, lo0);
  stA<0,1>(xb, ldsc, 0, gArow0, gArow1, gcol, lo0);
  stA<1,0>(xb, ldsc, 1, gArow0, gArow1, gcol, lo0);
  stB<1,0>(W,  ldsc, 1, gBrow0, gBrow1, gcol, lo0);
  WAIT_VM0(); BAR();

  #pragma unroll 1
  for (int i = 0; i < NKT / 2; ++i) {
    int t1 = 2 * i + 1;
    int t2 = 2 * i + 2; if (t2 > NKT - 1) t2 = NKT - 1;
    int t3 = 2 * i + 3; if (t3 > NKT - 1) t3 = NKT - 1;

    // ph1: buf0 M0 x {N0,N1}; stage buf1.B1,A1 <- t1 (read ph3/ph4, margin 2/3)
    lda<0,0>(ldsc, aRow, kOff, af);
    ldb<0,0>(ldsc, bRow, kOff, bq0);
    ldb<0,1>(ldsc, bRow, kOff, bq1);
    stB<1,1>(W,  ldsc, t1, gBrow0, gBrow1, gcol, lo0);
    stA<1,1>(xb, ldsc, t1, gArow0, gArow1, gcol, lo0);
    WAIT_LGKM8(); BAR(); WAIT_LGKM0();
    __builtin_amdgcn_s_setprio(1);
    mm<0,0>(af, bq0, acc);
    mm<0,1>(af, bq1, acc);
    __builtin_amdgcn_s_setprio(0);
    WAIT_VM4(); BAR();

    // ph2: buf0 M1 x {N0,N1}; stage buf0.A0,B0 <- t2 (read next ph1, margin 3)
    lda<0,1>(ldsc, aRow, kOff, af);
    stA<0,0>(xb, ldsc, t2, gArow0, gArow1, gcol, lo0);
    stB<0,0>(W,  ldsc, t2, gBrow0, gBrow1, gcol, lo0);
    BAR(); WAIT_LGKM0();
    __builtin_amdgcn_s_setprio(1);
    mm<1,0>(af, bq0, acc);
    mm<1,1>(af, bq1, acc);
    __builtin_amdgcn_s_setprio(0);
    WAIT_VM4(); BAR();

    // ph3: buf1 M0 x {N0,N1}; stage buf0.B1,A1 <- t2 (read next ph1/ph2, margin 2/3)
    lda<1,0>(ldsc, aRow, kOff, af);
    ldb<1,0>(ldsc, bRow, kOff, bq0);
    ldb<1,1>(ldsc, bRow, kOff, bq1);
    stB<0,1>(W,  ldsc, t2, gBrow0, gBrow1, gcol, lo0);
    stA<0,1>(xb, ldsc, t2, gArow0, gArow1, gcol, lo0);
    WAIT_LGKM8(); BAR(); WAIT_LGKM0();
    __builtin_amdgcn_s_setprio(1);
    mm<0,0>(af, bq0, acc);
    mm<0,1>(af, bq1, acc);
    __builtin_amdgcn_s_setprio(0);
    WAIT_VM4(); BAR();

    // ph4: buf1 M1 x {N0,N1}; stage buf1.A0,B0 <- t3 (read next ph3, margin 3)
    lda<1,1>(ldsc, aRow, kOff, af);
    stA<1,0>(xb, ldsc, t3, gArow0, gArow1, gcol, lo0);
    stB<1,0>(W,  ldsc, t3, gBrow0, gBrow1, gcol, lo0);
    BAR(); WAIT_LGKM0();
    __builtin_amdgcn_s_setprio(1);
    mm<1,0>(af, bq0, acc);
    mm<1,1>(af, bq1, acc);
    __builtin_amdgcn_s_setprio(0);
    WAIT_VM4(); BAR();
  }

  WAIT_VM0(); BAR();

  // epilogue: C/D layout col=lane&15, row=(lane>>4)*4+j
  #pragma unroll
  for (int am = 0; am < 8; ++am) {
    #pragma unroll
    for (int an = 0; an < 4; ++an) {
      int row0 = brow + wr * 128 + am * 16 + (lane >> 4) * 4;
      int col  = bcol + wc * 64 + an * 16 + (lane & 15);
      #pragma unroll
      for (int j = 0; j < 4; ++j)
        y[(size_t)(row0 + j) * M_W + col] = acc[am][an][j];
    }
  }
}

extern "C" void kernel_launch(void* const* d_in, const int* in_sizes, int n_in,
                              void* d_out, int out_size, void* d_ws, size_t ws_size,
                              hipStream_t stream) {
  const float* inp     = (const float*)d_in[0];
  const int*   trellis = (const int*)d_in[1];
  const float* tlut    = (const float*)d_in[2];
  float* y = (float*)d_out;

  unsigned short* xb = (unsigned short*)d_ws;
  unsigned short* Wd = (unsigned short*)((char*)d_ws + (size_t)M_X * K_DIM * 2);

  (void)hipFuncSetAttribute((const void*)gemm8_kernel,
                            hipFuncAttributeMaxDynamicSharedMemorySize, 131072);

  prep_kernel<<<49152, 256, 0, stream>>>(inp, trellis, tlut, xb, Wd);
  gemm8_kernel<<<dim3(512), dim3(512), 131072, stream>>>(xb, Wd, y);
}

// Round 10
// 267.292 us; speedup vs baseline: 1.1143x; 1.0092x over previous
//
#include <hip/hip_runtime.h>
#include <hip/hip_bf16.h>

#define AS1 __attribute__((address_space(1)))
#define AS3 __attribute__((address_space(3)))

typedef __bf16 bf16x8 __attribute__((ext_vector_type(8)));
typedef float f32x4 __attribute__((ext_vector_type(4)));

#define GLOAD_LDS16(gptr, lptr) \
  __builtin_amdgcn_global_load_lds((AS1 void*)(gptr), (AS3 void*)(lptr), 16, 0, 0)

#define M_W   4096
#define K_DIM 4096
#define M_X   8192
#define NT_T  65536
#define NKT   (K_DIM/64)

#define BAR()        __builtin_amdgcn_s_barrier()
#define WAIT_VM4()   asm volatile("s_waitcnt vmcnt(4)" ::: "memory")
#define WAIT_VM0()   asm volatile("s_waitcnt vmcnt(0)" ::: "memory")

__device__ __forceinline__ unsigned short f2bf(float f) {
  unsigned int u = __float_as_uint(f);
  unsigned int r = (u + 0x7FFFu + ((u >> 16) & 1u)) >> 16;
  return (unsigned short)r;
}

// ---------------- fused prep: x fp32->bf16 (1/3 of blocks) + trellis decode (2/3) ----------------
__global__ void prep_kernel(const float* __restrict__ x,
                            const int* __restrict__ trellis,
                            const float* __restrict__ tlut,
                            unsigned short* __restrict__ xb,
                            unsigned short* __restrict__ W) {
  int b = blockIdx.x;
  int tid = threadIdx.x;
  if (b % 3 == 0) {
    int idx = (b / 3) * 256 + tid;
    const float4* p = reinterpret_cast<const float4*>(x) + (size_t)idx * 2;
    float4 u = p[0];
    float4 v = p[1];
    uint4 o;
    o.x = (unsigned)f2bf(u.x) | ((unsigned)f2bf(u.y) << 16);
    o.y = (unsigned)f2bf(u.z) | ((unsigned)f2bf(u.w) << 16);
    o.z = (unsigned)f2bf(v.x) | ((unsigned)f2bf(v.y) << 16);
    o.w = (unsigned)f2bf(v.z) | ((unsigned)f2bf(v.w) << 16);
    reinterpret_cast<uint4*>(xb)[idx] = o;
  } else {
    int db = b - b / 3 - 1;
    int idx = db * 256 + tid;
    int t = idx >> 7;
    int s = idx & 127;
    const unsigned int* tr = reinterpret_cast<const unsigned int*>(trellis) + t * 32;
    int w0  = s >> 2;
    int off = (s & 3) * 4;
    unsigned int a = tr[w0] & 0xFFFFu;
    unsigned int state;
    if (off == 0) {
      state = a;
    } else {
      unsigned int bb = tr[(w0 + 1) & 31] & 0xFFFFu;
      state = ((a << off) | (bb >> (16 - off))) & 0xFFFFu;
    }
    unsigned int code = state & 0x1FFu;
    float2 v = reinterpret_cast<const float2*>(tlut)[code];
    int i = t >> 8;
    int j = t & 255;
    int flat = s * 2;
    int r = flat >> 4;
    int c = flat & 15;
    unsigned int packed = (unsigned)f2bf(v.x) | ((unsigned)f2bf(v.y) << 16);
    size_t o = (size_t)(i * 16 + r) * K_DIM + (j * 16 + c);
    *reinterpret_cast<unsigned int*>(W + o) = packed;
  }
}

// ---------------- 256x256 4-phase bf16 GEMM, compiler-counted lgkm waits ----------------
// y[8192,4096] = xb[8192,4096] * W[4096,4096]^T
// LDS slots: A(buf,half) = (buf*2+half)*16384 ; B(buf,half) = 65536 + (buf*2+half)*16384
// Half-tile: 128 rows x 64 cols bf16, 16B chunks XOR-swizzled (chunk ^= row&7).
// Phase = { ds_reads (consumption order); stage; BAR; MFMA (compiler inserts counted
// lgkmcnt, drain overlaps MFMA issue); VM4; BAR }. NO hand lgkm waits.

template<int BUF, int MH>
__device__ __forceinline__ void lda(const char* ldsc, const int* aRow, const int* kOff,
                                    bf16x8 (&af)[4][2]) {
  const char* base = ldsc + (BUF * 2 + MH) * 16384;
  #pragma unroll
  for (int fm = 0; fm < 4; ++fm)
    #pragma unroll
    for (int kh = 0; kh < 2; ++kh)
      af[fm][kh] = *(const bf16x8*)(base + aRow[fm] + kOff[kh]);
}

template<int BUF, int NH>
__device__ __forceinline__ void ldb(const char* ldsc, const int* bRow, const int* kOff,
                                    bf16x8 (&bq)[2][2]) {
  const char* base = ldsc + 65536 + (BUF * 2 + NH) * 16384;
  #pragma unroll
  for (int fn = 0; fn < 2; ++fn)
    #pragma unroll
    for (int kh = 0; kh < 2; ++kh)
      bq[fn][kh] = *(const bf16x8*)(base + bRow[fn] + kOff[kh]);
}

template<int MH, int NH>
__device__ __forceinline__ void mm(const bf16x8 (&af)[4][2], const bf16x8 (&bq)[2][2],
                                   f32x4 (&acc)[8][4]) {
  #pragma unroll
  for (int fm = 0; fm < 4; ++fm)
    #pragma unroll
    for (int fn = 0; fn < 2; ++fn)
      #pragma unroll
      for (int kh = 0; kh < 2; ++kh)
        acc[MH * 4 + fm][NH * 2 + fn] =
            __builtin_amdgcn_mfma_f32_16x16x32_bf16(af[fm][kh], bq[fn][kh],
                                                    acc[MH * 4 + fm][NH * 2 + fn], 0, 0, 0);
}

template<int BUF, int HALF>
__device__ __forceinline__ void stA(const unsigned short* xb, char* ldsc, int kt,
                                    int gArow0, int gArow1, int gcol, int lo0) {
  const unsigned short* s0 = xb + (size_t)(gArow0 + HALF * 64) * K_DIM + kt * 64 + gcol;
  const unsigned short* s1 = xb + (size_t)(gArow1 + HALF * 64) * K_DIM + kt * 64 + gcol;
  GLOAD_LDS16(s0, ldsc + (BUF * 2 + HALF) * 16384 + lo0);
  GLOAD_LDS16(s1, ldsc + (BUF * 2 + HALF) * 16384 + lo0 + 1024);
}

template<int BUF, int HALF>
__device__ __forceinline__ void stB(const unsigned short* W, char* ldsc, int kt,
                                    int gBrow0, int gBrow1, int gcol, int lo0) {
  const unsigned short* s0 = W + (size_t)(gBrow0 + HALF * 32) * K_DIM + kt * 64 + gcol;
  const unsigned short* s1 = W + (size_t)(gBrow1 + HALF * 32) * K_DIM + kt * 64 + gcol;
  GLOAD_LDS16(s0, ldsc + 65536 + (BUF * 2 + HALF) * 16384 + lo0);
  GLOAD_LDS16(s1, ldsc + 65536 + (BUF * 2 + HALF) * 16384 + lo0 + 1024);
}

__global__ __launch_bounds__(512) void gemm8_kernel(const unsigned short* __restrict__ xb,
                                                    const unsigned short* __restrict__ W,
                                                    float* __restrict__ y) {
  extern __shared__ __align__(16) char ldsc[];   // 131072 bytes

  int bid = blockIdx.x;
  int swz = (bid & 7) * 64 + (bid >> 3);
  int brow = (swz >> 4) * 256;
  int bcol = (swz & 15) * 256;

  int tid  = threadIdx.x;
  int lane = tid & 63;
  int wid  = tid >> 6;
  int wr = wid >> 2;
  int wc = wid & 3;

  int kOff[2], aRow[4], bRow[2];
  #pragma unroll
  for (int kh = 0; kh < 2; ++kh) kOff[kh] = ((kh * 4 + (lane >> 4)) ^ (lane & 7)) << 4;
  #pragma unroll
  for (int fm = 0; fm < 4; ++fm) aRow[fm] = (wr * 64 + fm * 16 + (lane & 15)) << 7;
  #pragma unroll
  for (int fn = 0; fn < 2; ++fn) bRow[fn] = (wc * 32 + fn * 16 + (lane & 15)) << 7;

  int q0 = wid * 16 + (lane >> 3);
  int q1 = q0 + 8;
  int lo0 = wid * 2048 + lane * 16;
  int gcol = ((lane & 7) ^ (lane >> 3)) << 3;
  int gArow0 = brow + (q0 >> 6) * 128 + (q0 & 63);
  int gArow1 = brow + (q1 >> 6) * 128 + (q1 & 63);
  int gBrow0 = bcol + (q0 >> 5) * 64 + (q0 & 31);
  int gBrow1 = bcol + (q1 >> 5) * 64 + (q1 & 31);

  f32x4 acc[8][4];
  #pragma unroll
  for (int m = 0; m < 8; ++m)
    #pragma unroll
    for (int n = 0; n < 4; ++n)
      acc[m][n] = (f32x4){0.f, 0.f, 0.f, 0.f};

  bf16x8 af[4][2];
  bf16x8 bq0[2][2], bq1[2][2];

  // prologue: buf0 <- t0 (A0,B0,B1,A1); buf1 <- t1 (A0,B0). buf1.B1/A1 staged at ph1.
  stA<0,0>(xb, ldsc, 0, gArow0, gArow1, gcol, lo0);
  stB<0,0>(W,  ldsc, 0, gBrow0, gBrow1, gcol, lo0);
  stB<0,1>(W,  ldsc, 0, gBrow0, gBrow1, gcol, lo0);
  stA<0,1>(xb, ldsc, 0, gArow0, gArow1, gcol, lo0);
  stA<1,0>(xb, ldsc, 1, gArow0, gArow1, gcol, lo0);
  stB<1,0>(W,  ldsc, 1, gBrow0, gBrow1, gcol, lo0);
  WAIT_VM0(); BAR();

  #pragma unroll 1
  for (int i = 0; i < NKT / 2; ++i) {
    int t1 = 2 * i + 1;
    int t2 = 2 * i + 2; if (t2 > NKT - 1) t2 = NKT - 1;
    int t3 = 2 * i + 3; if (t3 > NKT - 1) t3 = NKT - 1;

    // ph1: buf0 M0 x {N0,N1}; stage buf1.B1,A1 <- t1 (read ph3/ph4, margin 2/3)
    lda<0,0>(ldsc, aRow, kOff, af);
    ldb<0,0>(ldsc, bRow, kOff, bq0);
    ldb<0,1>(ldsc, bRow, kOff, bq1);
    stB<1,1>(W,  ldsc, t1, gBrow0, gBrow1, gcol, lo0);
    stA<1,1>(xb, ldsc, t1, gArow0, gArow1, gcol, lo0);
    BAR();
    __builtin_amdgcn_s_setprio(1);
    mm<0,0>(af, bq0, acc);
    mm<0,1>(af, bq1, acc);
    __builtin_amdgcn_s_setprio(0);
    WAIT_VM4(); BAR();

    // ph2: buf0 M1 x {N0,N1}; stage buf0.A0,B0 <- t2 (read next ph1, margin 3)
    lda<0,1>(ldsc, aRow, kOff, af);
    stA<0,0>(xb, ldsc, t2, gArow0, gArow1, gcol, lo0);
    stB<0,0>(W,  ldsc, t2, gBrow0, gBrow1, gcol, lo0);
    BAR();
    __builtin_amdgcn_s_setprio(1);
    mm<1,0>(af, bq0, acc);
    mm<1,1>(af, bq1, acc);
    __builtin_amdgcn_s_setprio(0);
    WAIT_VM4(); BAR();

    // ph3: buf1 M0 x {N0,N1}; stage buf0.B1,A1 <- t2 (read next ph1/ph2, margin 2/3)
    lda<1,0>(ldsc, aRow, kOff, af);
    ldb<1,0>(ldsc, bRow, kOff, bq0);
    ldb<1,1>(ldsc, bRow, kOff, bq1);
    stB<0,1>(W,  ldsc, t2, gBrow0, gBrow1, gcol, lo0);
    stA<0,1>(xb, ldsc, t2, gArow0, gArow1, gcol, lo0);
    BAR();
    __builtin_amdgcn_s_setprio(1);
    mm<0,0>(af, bq0, acc);
    mm<0,1>(af, bq1, acc);
    __builtin_amdgcn_s_setprio(0);
    WAIT_VM4(); BAR();

    // ph4: buf1 M1 x {N0,N1}; stage buf1.A0,B0 <- t3 (read next ph3, margin 3)
    lda<1,1>(ldsc, aRow, kOff, af);
    stA<1,0>(xb, ldsc, t3, gArow0, gArow1, gcol, lo0);
    stB<1,0>(W,  ldsc, t3, gBrow0, gBrow1, gcol, lo0);
    BAR();
    __builtin_amdgcn_s_setprio(1);
    mm<1,0>(af, bq0, acc);
    mm<1,1>(af, bq1, acc);
    __builtin_amdgcn_s_setprio(0);
    WAIT_VM4(); BAR();
  }

  WAIT_VM0(); BAR();

  // epilogue: C/D layout col=lane&15, row=(lane>>4)*4+j
  #pragma unroll
  for (int am = 0; am < 8; ++am) {
    #pragma unroll
    for (int an = 0; an < 4; ++an) {
      int row0 = brow + wr * 128 + am * 16 + (lane >> 4) * 4;
      int col  = bcol + wc * 64 + an * 16 + (lane & 15);
      #pragma unroll
      for (int j = 0; j < 4; ++j)
        y[(size_t)(row0 + j) * M_W + col] = acc[am][an][j];
    }
  }
}

extern "C" void kernel_launch(void* const* d_in, const int* in_sizes, int n_in,
                              void* d_out, int out_size, void* d_ws, size_t ws_size,
                              hipStream_t stream) {
  const float* inp     = (const float*)d_in[0];
  const int*   trellis = (const int*)d_in[1];
  const float* tlut    = (const float*)d_in[2];
  float* y = (float*)d_out;

  unsigned short* xb = (unsigned short*)d_ws;
  unsigned short* Wd = (unsigned short*)((char*)d_ws + (size_t)M_X * K_DIM * 2);

  (void)hipFuncSetAttribute((const void*)gemm8_kernel,
                            hipFuncAttributeMaxDynamicSharedMemorySize, 131072);

  prep_kernel<<<49152, 256, 0, stream>>>(inp, trellis, tlut, xb, Wd);
  gemm8_kernel<<<dim3(512), dim3(512), 131072, stream>>>(xb, Wd, y);
}

// Round 11
// 254.232 us; speedup vs baseline: 1.1716x; 1.0514x over previous
//
#include <hip/hip_runtime.h>
#include <hip/hip_bf16.h>

#define AS1 __attribute__((address_space(1)))
#define AS3 __attribute__((address_space(3)))

typedef __bf16 bf16x8 __attribute__((ext_vector_type(8)));
typedef float f32x4 __attribute__((ext_vector_type(4)));

#define GLOAD_LDS16(gptr, lptr) \
  __builtin_amdgcn_global_load_lds((AS1 void*)(gptr), (AS3 void*)(lptr), 16, 0, 0)

#define M_W   4096
#define K_DIM 4096
#define M_X   8192
#define NT_T  65536
#define NKT   (K_DIM/64)

#define BAR()        __builtin_amdgcn_s_barrier()
#define WAIT_VM4()   asm volatile("s_waitcnt vmcnt(4)" ::: "memory")
#define WAIT_VM0()   asm volatile("s_waitcnt vmcnt(0)" ::: "memory")

__device__ __forceinline__ unsigned short f2bf(float f) {
  unsigned int u = __float_as_uint(f);
  unsigned int r = (u + 0x7FFFu + ((u >> 16) & 1u)) >> 16;
  return (unsigned short)r;
}

// ---------------- fused prep: x fp32->bf16 (1/3 of blocks) + trellis decode (2/3) ----------------
__global__ void prep_kernel(const float* __restrict__ x,
                            const int* __restrict__ trellis,
                            const float* __restrict__ tlut,
                            unsigned short* __restrict__ xb,
                            unsigned short* __restrict__ W) {
  int b = blockIdx.x;
  int tid = threadIdx.x;
  if (b % 3 == 0) {
    int idx = (b / 3) * 256 + tid;
    const float4* p = reinterpret_cast<const float4*>(x) + (size_t)idx * 2;
    float4 u = p[0];
    float4 v = p[1];
    uint4 o;
    o.x = (unsigned)f2bf(u.x) | ((unsigned)f2bf(u.y) << 16);
    o.y = (unsigned)f2bf(u.z) | ((unsigned)f2bf(u.w) << 16);
    o.z = (unsigned)f2bf(v.x) | ((unsigned)f2bf(v.y) << 16);
    o.w = (unsigned)f2bf(v.z) | ((unsigned)f2bf(v.w) << 16);
    reinterpret_cast<uint4*>(xb)[idx] = o;
  } else {
    int db = b - b / 3 - 1;
    int idx = db * 256 + tid;
    int t = idx >> 7;
    int s = idx & 127;
    const unsigned int* tr = reinterpret_cast<const unsigned int*>(trellis) + t * 32;
    int w0  = s >> 2;
    int off = (s & 3) * 4;
    unsigned int a = tr[w0] & 0xFFFFu;
    unsigned int state;
    if (off == 0) {
      state = a;
    } else {
      unsigned int bb = tr[(w0 + 1) & 31] & 0xFFFFu;
      state = ((a << off) | (bb >> (16 - off))) & 0xFFFFu;
    }
    unsigned int code = state & 0x1FFu;
    float2 v = reinterpret_cast<const float2*>(tlut)[code];
    int i = t >> 8;
    int j = t & 255;
    int flat = s * 2;
    int r = flat >> 4;
    int c = flat & 15;
    unsigned int packed = (unsigned)f2bf(v.x) | ((unsigned)f2bf(v.y) << 16);
    size_t o = (size_t)(i * 16 + r) * K_DIM + (j * 16 + c);
    *reinterpret_cast<unsigned int*>(W + o) = packed;
  }
}

// ---------------- 256x256 4-phase GEMM, register read-ahead, 1 barrier/phase ----------------
// y[8192,4096] = xb[8192,4096] * W[4096,4096]^T
// LDS slots: A(buf,half) = (buf*2+half)*16384 ; B(buf,half) = 65536 + (buf*2+half)*16384
// Half-tile: 128 rows x 64 cols bf16, 16B chunks XOR-swizzled (chunk ^= row&7).
// Phase p: { 32 MFMA on frags read in p-1 (regs only); ds_reads for p+1; 2 stage-calls;
//            vmcnt(4); barrier }. NO sched fences, NO hand lgkm — compiler interleaves
// reads into the MFMA stream and places counted lgkm waits before next phase's MFMA.
// K-tile 2i -> phases p1,p2 (buf0); K-tile 2i+1 -> p3,p4 (buf1).
// Stage calendar: p1: buf0.A0,B0<-t2 | p2: buf0.B1,A1<-t2 | p3: buf1.A0,B0<-t3 | p4: buf1.B1,A1<-t3
// All slot stage->read margins 2-3 phases; VM4/phase (4 gloads/phase) forces 2-back complete.

template<int BUF, int MH>
__device__ __forceinline__ void lda(const char* ldsc, const int* aRow, const int* kOff,
                                    bf16x8 (&af)[4][2]) {
  const char* base = ldsc + (BUF * 2 + MH) * 16384;
  #pragma unroll
  for (int fm = 0; fm < 4; ++fm)
    #pragma unroll
    for (int kh = 0; kh < 2; ++kh)
      af[fm][kh] = *(const bf16x8*)(base + aRow[fm] + kOff[kh]);
}

template<int BUF, int NH>
__device__ __forceinline__ void ldb(const char* ldsc, const int* bRow, const int* kOff,
                                    bf16x8 (&bq)[2][2]) {
  const char* base = ldsc + 65536 + (BUF * 2 + NH) * 16384;
  #pragma unroll
  for (int fn = 0; fn < 2; ++fn)
    #pragma unroll
    for (int kh = 0; kh < 2; ++kh)
      bq[fn][kh] = *(const bf16x8*)(base + bRow[fn] + kOff[kh]);
}

// full M-half x all 4 n-frags: 32 MFMA
template<int MH>
__device__ __forceinline__ void mmF(const bf16x8 (&af)[4][2], const bf16x8 (&bq)[2][2][2],
                                    f32x4 (&acc)[8][4]) {
  __builtin_amdgcn_s_setprio(1);
  #pragma unroll
  for (int NH = 0; NH < 2; ++NH)
    #pragma unroll
    for (int fm = 0; fm < 4; ++fm)
      #pragma unroll
      for (int fn = 0; fn < 2; ++fn)
        #pragma unroll
        for (int kh = 0; kh < 2; ++kh)
          acc[MH * 4 + fm][NH * 2 + fn] =
              __builtin_amdgcn_mfma_f32_16x16x32_bf16(af[fm][kh], bq[NH][fn][kh],
                                                      acc[MH * 4 + fm][NH * 2 + fn], 0, 0, 0);
  __builtin_amdgcn_s_setprio(0);
}

template<int BUF, int HALF>
__device__ __forceinline__ void stA(const unsigned short* xb, char* ldsc, int kt,
                                    int gArow0, int gArow1, int gcol, int lo0) {
  const unsigned short* s0 = xb + (size_t)(gArow0 + HALF * 64) * K_DIM + kt * 64 + gcol;
  const unsigned short* s1 = xb + (size_t)(gArow1 + HALF * 64) * K_DIM + kt * 64 + gcol;
  GLOAD_LDS16(s0, ldsc + (BUF * 2 + HALF) * 16384 + lo0);
  GLOAD_LDS16(s1, ldsc + (BUF * 2 + HALF) * 16384 + lo0 + 1024);
}

template<int BUF, int HALF>
__device__ __forceinline__ void stB(const unsigned short* W, char* ldsc, int kt,
                                    int gBrow0, int gBrow1, int gcol, int lo0) {
  const unsigned short* s0 = W + (size_t)(gBrow0 + HALF * 32) * K_DIM + kt * 64 + gcol;
  const unsigned short* s1 = W + (size_t)(gBrow1 + HALF * 32) * K_DIM + kt * 64 + gcol;
  GLOAD_LDS16(s0, ldsc + 65536 + (BUF * 2 + HALF) * 16384 + lo0);
  GLOAD_LDS16(s1, ldsc + 65536 + (BUF * 2 + HALF) * 16384 + lo0 + 1024);
}

__global__ __launch_bounds__(512) void gemm8_kernel(const unsigned short* __restrict__ xb,
                                                    const unsigned short* __restrict__ W,
                                                    float* __restrict__ y) {
  extern __shared__ __align__(16) char ldsc[];   // 131072 bytes

  int bid = blockIdx.x;
  int swz = (bid & 7) * 64 + (bid >> 3);
  int brow = (swz >> 4) * 256;
  int bcol = (swz & 15) * 256;

  int tid  = threadIdx.x;
  int lane = tid & 63;
  int wid  = tid >> 6;
  int wr = wid >> 2;
  int wc = wid & 3;

  int kOff[2], aRow[4], bRow[2];
  #pragma unroll
  for (int kh = 0; kh < 2; ++kh) kOff[kh] = ((kh * 4 + (lane >> 4)) ^ (lane & 7)) << 4;
  #pragma unroll
  for (int fm = 0; fm < 4; ++fm) aRow[fm] = (wr * 64 + fm * 16 + (lane & 15)) << 7;
  #pragma unroll
  for (int fn = 0; fn < 2; ++fn) bRow[fn] = (wc * 32 + fn * 16 + (lane & 15)) << 7;

  int q0 = wid * 16 + (lane >> 3);
  int q1 = q0 + 8;
  int lo0 = wid * 2048 + lane * 16;
  int gcol = ((lane & 7) ^ (lane >> 3)) << 3;
  int gArow0 = brow + (q0 >> 6) * 128 + (q0 & 63);
  int gArow1 = brow + (q1 >> 6) * 128 + (q1 & 63);
  int gBrow0 = bcol + (q0 >> 5) * 64 + (q0 & 31);
  int gBrow1 = bcol + (q1 >> 5) * 64 + (q1 & 31);

  f32x4 acc[8][4];
  #pragma unroll
  for (int m = 0; m < 8; ++m)
    #pragma unroll
    for (int n = 0; n < 4; ++n)
      acc[m][n] = (f32x4){0.f, 0.f, 0.f, 0.f};

  bf16x8 afA[4][2], afB[4][2];       // A fragment double-buffer
  bf16x8 bqE[2][2][2], bqO[2][2][2]; // B fragments: even K-tile (buf0), odd K-tile (buf1)

  // prologue: buf0 <- t0 (all 4 slots), buf1 <- t1 (all 4 slots)
  stA<0,0>(xb, ldsc, 0, gArow0, gArow1, gcol, lo0);
  stB<0,0>(W,  ldsc, 0, gBrow0, gBrow1, gcol, lo0);
  stB<0,1>(W,  ldsc, 0, gBrow0, gBrow1, gcol, lo0);
  stA<0,1>(xb, ldsc, 0, gArow0, gArow1, gcol, lo0);
  stA<1,0>(xb, ldsc, 1, gArow0, gArow1, gcol, lo0);
  stB<1,0>(W,  ldsc, 1, gBrow0, gBrow1, gcol, lo0);
  stB<1,1>(W,  ldsc, 1, gBrow0, gBrow1, gcol, lo0);
  stA<1,1>(xb, ldsc, 1, gArow0, gArow1, gcol, lo0);
  WAIT_VM0(); BAR();

  // preloop reads for p1(i=0): afA <- buf0.A0, bqE <- buf0.{B0,B1}
  lda<0,0>(ldsc, aRow, kOff, afA);
  ldb<0,0>(ldsc, bRow, kOff, bqE[0]);
  ldb<0,1>(ldsc, bRow, kOff, bqE[1]);

  #pragma unroll 1
  for (int i = 0; i < NKT / 2; ++i) {
    int t2 = 2 * i + 2; if (t2 > NKT - 1) t2 = NKT - 1;
    int t3 = 2 * i + 3; if (t3 > NKT - 1) t3 = NKT - 1;

    // p1: K-tile 2i, M-half0; read buf0.A1 -> afB; stage buf0.A0,B0 <- t2
    mmF<0>(afA, bqE, acc);
    lda<0,1>(ldsc, aRow, kOff, afB);
    stA<0,0>(xb, ldsc, t2, gArow0, gArow1, gcol, lo0);
    stB<0,0>(W,  ldsc, t2, gBrow0, gBrow1, gcol, lo0);
    WAIT_VM4(); BAR();

    // p2: K-tile 2i, M-half1; read buf1.A0 -> afA, buf1.{B0,B1} -> bqO; stage buf0.B1,A1 <- t2
    mmF<1>(afB, bqE, acc);
    lda<1,0>(ldsc, aRow, kOff, afA);
    ldb<1,0>(ldsc, bRow, kOff, bqO[0]);
    ldb<1,1>(ldsc, bRow, kOff, bqO[1]);
    stB<0,1>(W,  ldsc, t2, gBrow0, gBrow1, gcol, lo0);
    stA<0,1>(xb, ldsc, t2, gArow0, gArow1, gcol, lo0);
    WAIT_VM4(); BAR();

    // p3: K-tile 2i+1, M-half0; read buf1.A1 -> afB; stage buf1.A0,B0 <- t3
    mmF<0>(afA, bqO, acc);
    lda<1,1>(ldsc, aRow, kOff, afB);
    stA<1,0>(xb, ldsc, t3, gArow0, gArow1, gcol, lo0);
    stB<1,0>(W,  ldsc, t3, gBrow0, gBrow1, gcol, lo0);
    WAIT_VM4(); BAR();

    // p4: K-tile 2i+1, M-half1; read buf0.A0 -> afA (t2 data), buf0.{B0,B1} -> bqE;
    //     stage buf1.B1,A1 <- t3
    mmF<1>(afB, bqO, acc);
    lda<0,0>(ldsc, aRow, kOff, afA);
    ldb<0,0>(ldsc, bRow, kOff, bqE[0]);
    ldb<0,1>(ldsc, bRow, kOff, bqE[1]);
    stB<1,1>(W,  ldsc, t3, gBrow0, gBrow1, gcol, lo0);
    stA<1,1>(xb, ldsc, t3, gArow0, gArow1, gcol, lo0);
    WAIT_VM4(); BAR();
  }

  WAIT_VM0();

  // epilogue: C/D layout col=lane&15, row=(lane>>4)*4+j
  #pragma unroll
  for (int am = 0; am < 8; ++am) {
    #pragma unroll
    for (int an = 0; an < 4; ++an) {
      int row0 = brow + wr * 128 + am * 16 + (lane >> 4) * 4;
      int col  = bcol + wc * 64 + an * 16 + (lane & 15);
      #pragma unroll
      for (int j = 0; j < 4; ++j)
        y[(size_t)(row0 + j) * M_W + col] = acc[am][an][j];
    }
  }
}

extern "C" void kernel_launch(void* const* d_in, const int* in_sizes, int n_in,
                              void* d_out, int out_size, void* d_ws, size_t ws_size,
                              hipStream_t stream) {
  const float* inp     = (const float*)d_in[0];
  const int*   trellis = (const int*)d_in[1];
  const float* tlut    = (const float*)d_in[2];
  float* y = (float*)d_out;

  unsigned short* xb = (unsigned short*)d_ws;
  unsigned short* Wd = (unsigned short*)((char*)d_ws + (size_t)M_X * K_DIM * 2);

  (void)hipFuncSetAttribute((const void*)gemm8_kernel,
                            hipFuncAttributeMaxDynamicSharedMemorySize, 131072);

  prep_kernel<<<49152, 256, 0, stream>>>(inp, trellis, tlut, xb, Wd);
  gemm8_kernel<<<dim3(512), dim3(512), 131072, stream>>>(xb, Wd, y);
}

// Round 12
// 251.849 us; speedup vs baseline: 1.1827x; 1.0095x over previous
//
#include <hip/hip_runtime.h>
#include <hip/hip_bf16.h>

#define AS1 __attribute__((address_space(1)))
#define AS3 __attribute__((address_space(3)))

typedef __bf16 bf16x8 __attribute__((ext_vector_type(8)));
typedef float f32x4 __attribute__((ext_vector_type(4)));

#define GLOAD_LDS16(gptr, lptr) \
  __builtin_amdgcn_global_load_lds((AS1 void*)(gptr), (AS3 void*)(lptr), 16, 0, 0)

#define M_W   4096
#define K_DIM 4096
#define M_X   8192
#define NT_T  65536
#define NKT   (K_DIM/64)

#define BAR()        __builtin_amdgcn_s_barrier()
#define WAIT_VM4()   asm volatile("s_waitcnt vmcnt(4)" ::: "memory")
#define WAIT_VM0()   asm volatile("s_waitcnt vmcnt(0)" ::: "memory")

__device__ __forceinline__ unsigned short f2bf(float f) {
  unsigned int u = __float_as_uint(f);
  unsigned int r = (u + 0x7FFFu + ((u >> 16) & 1u)) >> 16;
  return (unsigned short)r;
}

// ---------------- fused prep: x fp32->bf16 (1/3 of blocks) + trellis decode (2/3) ----------------
__global__ void prep_kernel(const float* __restrict__ x,
                            const int* __restrict__ trellis,
                            const float* __restrict__ tlut,
                            unsigned short* __restrict__ xb,
                            unsigned short* __restrict__ W) {
  int b = blockIdx.x;
  int tid = threadIdx.x;
  if (b % 3 == 0) {
    int idx = (b / 3) * 256 + tid;
    const float4* p = reinterpret_cast<const float4*>(x) + (size_t)idx * 2;
    float4 u = p[0];
    float4 v = p[1];
    uint4 o;
    o.x = (unsigned)f2bf(u.x) | ((unsigned)f2bf(u.y) << 16);
    o.y = (unsigned)f2bf(u.z) | ((unsigned)f2bf(u.w) << 16);
    o.z = (unsigned)f2bf(v.x) | ((unsigned)f2bf(v.y) << 16);
    o.w = (unsigned)f2bf(v.z) | ((unsigned)f2bf(v.w) << 16);
    reinterpret_cast<uint4*>(xb)[idx] = o;
  } else {
    int db = b - b / 3 - 1;
    int idx = db * 256 + tid;
    int t = idx >> 7;
    int s = idx & 127;
    const unsigned int* tr = reinterpret_cast<const unsigned int*>(trellis) + t * 32;
    int w0  = s >> 2;
    int off = (s & 3) * 4;
    unsigned int a = tr[w0] & 0xFFFFu;
    unsigned int state;
    if (off == 0) {
      state = a;
    } else {
      unsigned int bb = tr[(w0 + 1) & 31] & 0xFFFFu;
      state = ((a << off) | (bb >> (16 - off))) & 0xFFFFu;
    }
    unsigned int code = state & 0x1FFu;
    float2 v = reinterpret_cast<const float2*>(tlut)[code];
    int i = t >> 8;
    int j = t & 255;
    int flat = s * 2;
    int r = flat >> 4;
    int c = flat & 15;
    unsigned int packed = (unsigned)f2bf(v.x) | ((unsigned)f2bf(v.y) << 16);
    size_t o = (size_t)(i * 16 + r) * K_DIM + (j * 16 + c);
    *reinterpret_cast<unsigned int*>(W + o) = packed;
  }
}

// ---------------- 256x256 4-phase GEMM, register read-ahead, 1 barrier/phase ----------------
// y[8192,4096] = xb[8192,4096] * W[4096,4096]^T
// LDS slots: A(buf,half) = (buf*2+half)*16384 ; B(buf,half) = 65536 + (buf*2+half)*16384
// Half-tile: 128 rows x 64 cols bf16, 16B chunks XOR-swizzled (chunk ^= row&7).
// Phase p: { 32 MFMA on frags read in p-1 (regs only); ds_reads for p+1; 2 stage-calls;
//            vmcnt(4); barrier }. NO sched fences, NO hand lgkm.
// R12 change: kh loop hoisted OUTERMOST in mmF -> same-acc dependent MFMAs are 8 apart
// (was distance 1), eliminating any back-to-back same-D accumulation hazard padding.

template<int BUF, int MH>
__device__ __forceinline__ void lda(const char* ldsc, const int* aRow, const int* kOff,
                                    bf16x8 (&af)[4][2]) {
  const char* base = ldsc + (BUF * 2 + MH) * 16384;
  #pragma unroll
  for (int fm = 0; fm < 4; ++fm)
    #pragma unroll
    for (int kh = 0; kh < 2; ++kh)
      af[fm][kh] = *(const bf16x8*)(base + aRow[fm] + kOff[kh]);
}

template<int BUF, int NH>
__device__ __forceinline__ void ldb(const char* ldsc, const int* bRow, const int* kOff,
                                    bf16x8 (&bq)[2][2]) {
  const char* base = ldsc + 65536 + (BUF * 2 + NH) * 16384;
  #pragma unroll
  for (int fn = 0; fn < 2; ++fn)
    #pragma unroll
    for (int kh = 0; kh < 2; ++kh)
      bq[fn][kh] = *(const bf16x8*)(base + bRow[fn] + kOff[kh]);
}

// full M-half x all 4 n-frags: 32 MFMA; kh OUTER so same-acc pairs are 8 apart
template<int MH>
__device__ __forceinline__ void mmF(const bf16x8 (&af)[4][2], const bf16x8 (&bq)[2][2][2],
                                    f32x4 (&acc)[8][4]) {
  __builtin_amdgcn_s_setprio(1);
  #pragma unroll
  for (int kh = 0; kh < 2; ++kh)
    #pragma unroll
    for (int NH = 0; NH < 2; ++NH)
      #pragma unroll
      for (int fm = 0; fm < 4; ++fm)
        #pragma unroll
        for (int fn = 0; fn < 2; ++fn)
          acc[MH * 4 + fm][NH * 2 + fn] =
              __builtin_amdgcn_mfma_f32_16x16x32_bf16(af[fm][kh], bq[NH][fn][kh],
                                                      acc[MH * 4 + fm][NH * 2 + fn], 0, 0, 0);
  __builtin_amdgcn_s_setprio(0);
}

template<int BUF, int HALF>
__device__ __forceinline__ void stA(const unsigned short* xb, char* ldsc, int kt,
                                    int gArow0, int gArow1, int gcol, int lo0) {
  const unsigned short* s0 = xb + (size_t)(gArow0 + HALF * 64) * K_DIM + kt * 64 + gcol;
  const unsigned short* s1 = xb + (size_t)(gArow1 + HALF * 64) * K_DIM + kt * 64 + gcol;
  GLOAD_LDS16(s0, ldsc + (BUF * 2 + HALF) * 16384 + lo0);
  GLOAD_LDS16(s1, ldsc + (BUF * 2 + HALF) * 16384 + lo0 + 1024);
}

template<int BUF, int HALF>
__device__ __forceinline__ void stB(const unsigned short* W, char* ldsc, int kt,
                                    int gBrow0, int gBrow1, int gcol, int lo0) {
  const unsigned short* s0 = W + (size_t)(gBrow0 + HALF * 32) * K_DIM + kt * 64 + gcol;
  const unsigned short* s1 = W + (size_t)(gBrow1 + HALF * 32) * K_DIM + kt * 64 + gcol;
  GLOAD_LDS16(s0, ldsc + 65536 + (BUF * 2 + HALF) * 16384 + lo0);
  GLOAD_LDS16(s1, ldsc + 65536 + (BUF * 2 + HALF) * 16384 + lo0 + 1024);
}

__global__ __launch_bounds__(512) void gemm8_kernel(const unsigned short* __restrict__ xb,
                                                    const unsigned short* __restrict__ W,
                                                    float* __restrict__ y) {
  extern __shared__ __align__(16) char ldsc[];   // 131072 bytes

  int bid = blockIdx.x;
  int swz = (bid & 7) * 64 + (bid >> 3);
  int brow = (swz >> 4) * 256;
  int bcol = (swz & 15) * 256;

  int tid  = threadIdx.x;
  int lane = tid & 63;
  int wid  = tid >> 6;
  int wr = wid >> 2;
  int wc = wid & 3;

  int kOff[2], aRow[4], bRow[2];
  #pragma unroll
  for (int kh = 0; kh < 2; ++kh) kOff[kh] = ((kh * 4 + (lane >> 4)) ^ (lane & 7)) << 4;
  #pragma unroll
  for (int fm = 0; fm < 4; ++fm) aRow[fm] = (wr * 64 + fm * 16 + (lane & 15)) << 7;
  #pragma unroll
  for (int fn = 0; fn < 2; ++fn) bRow[fn] = (wc * 32 + fn * 16 + (lane & 15)) << 7;

  int q0 = wid * 16 + (lane >> 3);
  int q1 = q0 + 8;
  int lo0 = wid * 2048 + lane * 16;
  int gcol = ((lane & 7) ^ (lane >> 3)) << 3;
  int gArow0 = brow + (q0 >> 6) * 128 + (q0 & 63);
  int gArow1 = brow + (q1 >> 6) * 128 + (q1 & 63);
  int gBrow0 = bcol + (q0 >> 5) * 64 + (q0 & 31);
  int gBrow1 = bcol + (q1 >> 5) * 64 + (q1 & 31);

  f32x4 acc[8][4];
  #pragma unroll
  for (int m = 0; m < 8; ++m)
    #pragma unroll
    for (int n = 0; n < 4; ++n)
      acc[m][n] = (f32x4){0.f, 0.f, 0.f, 0.f};

  bf16x8 afA[4][2], afB[4][2];       // A fragment double-buffer
  bf16x8 bqE[2][2][2], bqO[2][2][2]; // B fragments: even K-tile (buf0), odd K-tile (buf1)

  // prologue: buf0 <- t0 (all 4 slots), buf1 <- t1 (all 4 slots)
  stA<0,0>(xb, ldsc, 0, gArow0, gArow1, gcol, lo0);
  stB<0,0>(W,  ldsc, 0, gBrow0, gBrow1, gcol, lo0);
  stB<0,1>(W,  ldsc, 0, gBrow0, gBrow1, gcol, lo0);
  stA<0,1>(xb, ldsc, 0, gArow0, gArow1, gcol, lo0);
  stA<1,0>(xb, ldsc, 1, gArow0, gArow1, gcol, lo0);
  stB<1,0>(W,  ldsc, 1, gBrow0, gBrow1, gcol, lo0);
  stB<1,1>(W,  ldsc, 1, gBrow0, gBrow1, gcol, lo0);
  stA<1,1>(xb, ldsc, 1, gArow0, gArow1, gcol, lo0);
  WAIT_VM0(); BAR();

  // preloop reads for p1(i=0): afA <- buf0.A0, bqE <- buf0.{B0,B1}
  lda<0,0>(ldsc, aRow, kOff, afA);
  ldb<0,0>(ldsc, bRow, kOff, bqE[0]);
  ldb<0,1>(ldsc, bRow, kOff, bqE[1]);

  #pragma unroll 1
  for (int i = 0; i < NKT / 2; ++i) {
    int t2 = 2 * i + 2; if (t2 > NKT - 1) t2 = NKT - 1;
    int t3 = 2 * i + 3; if (t3 > NKT - 1) t3 = NKT - 1;

    // p1: K-tile 2i, M-half0; read buf0.A1 -> afB; stage buf0.A0,B0 <- t2
    mmF<0>(afA, bqE, acc);
    lda<0,1>(ldsc, aRow, kOff, afB);
    stA<0,0>(xb, ldsc, t2, gArow0, gArow1, gcol, lo0);
    stB<0,0>(W,  ldsc, t2, gBrow0, gBrow1, gcol, lo0);
    WAIT_VM4(); BAR();

    // p2: K-tile 2i, M-half1; read buf1.A0 -> afA, buf1.{B0,B1} -> bqO; stage buf0.B1,A1 <- t2
    mmF<1>(afB, bqE, acc);
    lda<1,0>(ldsc, aRow, kOff, afA);
    ldb<1,0>(ldsc, bRow, kOff, bqO[0]);
    ldb<1,1>(ldsc, bRow, kOff, bqO[1]);
    stB<0,1>(W,  ldsc, t2, gBrow0, gBrow1, gcol, lo0);
    stA<0,1>(xb, ldsc, t2, gArow0, gArow1, gcol, lo0);
    WAIT_VM4(); BAR();

    // p3: K-tile 2i+1, M-half0; read buf1.A1 -> afB; stage buf1.A0,B0 <- t3
    mmF<0>(afA, bqO, acc);
    lda<1,1>(ldsc, aRow, kOff, afB);
    stA<1,0>(xb, ldsc, t3, gArow0, gArow1, gcol, lo0);
    stB<1,0>(W,  ldsc, t3, gBrow0, gBrow1, gcol, lo0);
    WAIT_VM4(); BAR();

    // p4: K-tile 2i+1, M-half1; read buf0.A0 -> afA (t2 data), buf0.{B0,B1} -> bqE;
    //     stage buf1.B1,A1 <- t3
    mmF<1>(afB, bqO, acc);
    lda<0,0>(ldsc, aRow, kOff, afA);
    ldb<0,0>(ldsc, bRow, kOff, bqE[0]);
    ldb<0,1>(ldsc, bRow, kOff, bqE[1]);
    stB<1,1>(W,  ldsc, t3, gBrow0, gBrow1, gcol, lo0);
    stA<1,1>(xb, ldsc, t3, gArow0, gArow1, gcol, lo0);
    WAIT_VM4(); BAR();
  }

  WAIT_VM0();

  // epilogue: C/D layout col=lane&15, row=(lane>>4)*4+j
  #pragma unroll
  for (int am = 0; am < 8; ++am) {
    #pragma unroll
    for (int an = 0; an < 4; ++an) {
      int row0 = brow + wr * 128 + am * 16 + (lane >> 4) * 4;
      int col  = bcol + wc * 64 + an * 16 + (lane & 15);
      #pragma unroll
      for (int j = 0; j < 4; ++j)
        y[(size_t)(row0 + j) * M_W + col] = acc[am][an][j];
    }
  }
}

extern "C" void kernel_launch(void* const* d_in, const int* in_sizes, int n_in,
                              void* d_out, int out_size, void* d_ws, size_t ws_size,
                              hipStream_t stream) {
  const float* inp     = (const float*)d_in[0];
  const int*   trellis = (const int*)d_in[1];
  const float* tlut    = (const float*)d_in[2];
  float* y = (float*)d_out;

  unsigned short* xb = (unsigned short*)d_ws;
  unsigned short* Wd = (unsigned short*)((char*)d_ws + (size_t)M_X * K_DIM * 2);

  (void)hipFuncSetAttribute((const void*)gemm8_kernel,
                            hipFuncAttributeMaxDynamicSharedMemorySize, 131072);

  prep_kernel<<<49152, 256, 0, stream>>>(inp, trellis, tlut, xb, Wd);
  gemm8_kernel<<<dim3(512), dim3(512), 131072, stream>>>(xb, Wd, y);
}